// Round 11
// baseline (130.145 us; speedup 1.0000x reference)
//
#include <hip/hip_runtime.h>
#include <float.h>

// VectorQuantizer: x [64,64,32,32] f32, weight [1024,64] f32
// out[n] = weight[argmin_k ||x_n - w_k||^2]
// score = 0.5||w||^2 + (-x).w via split-bf16 MFMA, K=192 (hi.hi + lo.hi + hi.lo).
// R11: LPB=128 (keep 6:1 MFMA:ds_read amortization) x CPK=64 (LDS 67->35KB,
// acc 64->32 regs) -> ~145 unified regs, launch_bounds(256,3): 3 blocks/CU,
// 12 waves/CU (R9 was reg+LDS-capped at 2 blocks/8 waves, 50% stall).
// B staged via global_load_lds double-buffer (prefetch one phase ahead).
// Fold embeds vid=ch*2+ct (5 bits) in score's low mantissa; exact lex (score,k)
// epilogue; ambiguous latents rescored exactly inline (wave per latent).
// NOTE: no pointer ARRAYS into LDS (addrspacecast static-init fails on gfx950).
#define NLAT   65536
#define KCODES 1024
#define DIM    64
#define HW     1024
#define LPB    128
#define CPK    64
#define NCHUNK 16
#define XROW   136          // XE padded row (shorts): 272 B

typedef float f32x4 __attribute__((ext_vector_type(4)));
typedef short short8 __attribute__((ext_vector_type(8)));

static __device__ __forceinline__ unsigned short f2bf(float f) {
    unsigned int u = __float_as_uint(f);
    return (unsigned short)((u + 0x7fffu + ((u >> 16) & 1u)) >> 16);   // RNE
}
static __device__ __forceinline__ float bf2f(unsigned short h) {
    return __uint_as_float(((unsigned int)h) << 16);
}
static __device__ __forceinline__ void async_cp16(const void* g, void* l) {
    __builtin_amdgcn_global_load_lds(
        (const __attribute__((address_space(1))) unsigned int*)g,
        (__attribute__((address_space(3))) unsigned int*)l, 16, 0, 0);
}

// ---------------------------------------------------------------------------
// Prep: WEg[k] = 256B row of 16 swizzled 16B segs. Logical seg L: L<8 ->
// hi(d=8L..8L+7), L>=8 -> lo. Physical pos = L ^ (k & 15) (bank swizzle baked
// into global so the byte-linear DMA lands conflict-reduced for MFMA reads).
__global__ void vq_prep(const float* __restrict__ w, unsigned short* __restrict__ WEg,
                        float* __restrict__ wn) {
    int k = blockIdx.x * blockDim.x + threadIdx.x;   // 4 x 256 = 1024
    if (k >= KCODES) return;
    float s = 0.f;
    #pragma unroll
    for (int d = 0; d < DIM; ++d) { float v = w[(size_t)k * DIM + d]; s += v * v; }
    wn[k] = 0.5f * s;
    unsigned short* row = WEg + (size_t)k * 128;
    #pragma unroll
    for (int L = 0; L < 16; ++L) {
        short8 seg;
        #pragma unroll
        for (int j = 0; j < 8; ++j) {
            float v = w[(size_t)k * DIM + (L & 7) * 8 + j];
            unsigned short h = f2bf(v);
            seg[j] = (L < 8) ? (short)h : (short)f2bf(v - bf2f(h));
        }
        *(short8*)(row + ((L ^ (k & 15)) << 3)) = seg;
    }
}

// ---------------------------------------------------------------------------
// Main: 512 blocks x 256 thr (2 latent-halves x 2 code-halves). Wave tile:
// 64 lats x 32 codes per 64-code chunk (4x2 16x16 mfma tiles, 6 K-steps).
// A-frags (negated x) pinned in regs; B dbuf'd in LDS via async DMA.
__global__ __launch_bounds__(256, 3)
void vq_main(const float* __restrict__ x, const float* __restrict__ w,
             const unsigned short* __restrict__ WEg, const float* __restrict__ wn,
             float* __restrict__ out) {
    __shared__ __align__(16) char smem[35872];
    unsigned short* XE = (unsigned short*)smem;        // [128][136] (phase 0 only)
    char* wbuf0 = smem;                                // 16KB B buf (even chunks)
    char* wbuf1 = smem + 16384;                        // 16KB B buf (odd chunks)
    float* red  = (float*)smem;                        // [32][129] f32 (post-K)
    int*   redk = (int*)(smem + 16512);                // [32][129] int (post-K)
    int*   bfin = (int*)(smem + 34816);                // [128] winner k
    int*   amb  = (int*)(smem + 35328);                // [128] ambiguous lat ids
    int*   ambn = (int*)(smem + 35840);                // count

    const int tid  = threadIdx.x;
    const int wave = tid >> 6, lane = tid & 63;
    const int r16  = lane & 15, quad = lane >> 4;
    const int LH = wave & 1, CH = wave >> 1;

    const int blk = blockIdx.x;
    const int b   = blk >> 3;                 // 8 blocks per image
    const int hw0 = (blk & 7) * LPB;

    if (tid == 0) ambn[0] = 0;

    // Phase 0: convert NEGATED x tile -> XE[lat][hi 0..63 | lo 64..127]
    {
        const int lat  = tid & 127;
        const int half = tid >> 7;
        const float* xb = x + (size_t)b * (DIM * HW) + hw0 + lat;
        #pragma unroll 8
        for (int c = 0; c < 32; ++c) {
            int chn = half * 32 + c;
            float v = -xb[chn * HW];          // negate: score = wn + (-x).w
            unsigned short h = f2bf(v);
            XE[lat * XROW + chn]      = h;
            XE[lat * XROW + 64 + chn] = f2bf(v - bf2f(h));
        }
    }
    __syncthreads();

    // A-frags: span 0=hi d0-31, 1=hi d32-63, 2=lo d0-31, 3=lo d32-63
    short8 areg[4][4];
    #pragma unroll
    for (int lt = 0; lt < 4; ++lt)
        #pragma unroll
        for (int p = 0; p < 4; ++p)
            areg[lt][p] = *(const short8*)&XE[(LH * 64 + lt * 16 + r16) * XROW + p * 32 + quad * 8];
    __syncthreads();   // XE dead -> wbuf may overwrite

    // Prefetch chunk 0 into wbuf0 (drained by the first loop-top barrier)
    {
        const char* gsrc = (const char*)WEg + wave * 4096 + lane * 16;
        char* ldst = wbuf0 + wave * 4096;
        #pragma unroll
        for (int i = 0; i < 4; ++i) async_cp16(gsrc + i * 1024, ldst + i * 1024);
    }

    float b1[16], b2[16];
    #pragma unroll
    for (int sl = 0; sl < 16; ++sl) { b1[sl] = FLT_MAX; b2[sl] = FLT_MAX; }

    for (int ch = 0; ch < NCHUNK; ++ch) {
        __syncthreads();   // drains chunk-ch DMA (issued one full phase ago)
        if (ch + 1 < NCHUNK) {   // prefetch next chunk into the other buffer
            const char* gsrc = (const char*)WEg + (ch + 1) * 16384 + wave * 4096 + lane * 16;
            char* ldst = (((ch + 1) & 1) ? wbuf1 : wbuf0) + wave * 4096;
            #pragma unroll
            for (int i = 0; i < 4; ++i) async_cp16(gsrc + i * 1024, ldst + i * 1024);
        }
        const char* cbuf = (ch & 1) ? wbuf1 : wbuf0;
        const int kb = ch * CPK;

        float wnv[2];
        #pragma unroll
        for (int ct = 0; ct < 2; ++ct)
            wnv[ct] = wn[kb + CH * 32 + ct * 16 + r16];
        f32x4 acc[4][2];
        #pragma unroll
        for (int lt = 0; lt < 4; ++lt)
            #pragma unroll
            for (int ct = 0; ct < 2; ++ct) {
                acc[lt][ct][0] = wnv[ct]; acc[lt][ct][1] = wnv[ct];
                acc[lt][ct][2] = wnv[ct]; acc[lt][ct][3] = wnv[ct];
            }

        // K=192, W-span loaded once each: (A0,W0)(A2,W0)(A1,W1)(A3,W1)(A0,W2)(A1,W3)
        const int AI[6]  = {0, 2, 1, 3, 0, 1};
        const int WSp[6] = {0, 0, 1, 1, 2, 3};
        short8 bf[2];
        #pragma unroll
        for (int s = 0; s < 6; ++s) {
            if (s == 0 || WSp[s] != WSp[s - 1]) {
                #pragma unroll
                for (int ct = 0; ct < 2; ++ct) {
                    int r = CH * 32 + ct * 16 + r16;       // local code row 0..63
                    int seg = (WSp[s] * 4 + quad) ^ r16;   // matches prep swizzle
                    bf[ct] = *(const short8*)(cbuf + r * 256 + seg * 16);
                }
            }
            #pragma unroll
            for (int lt = 0; lt < 4; ++lt)
                #pragma unroll
                for (int ct = 0; ct < 2; ++ct)
                    acc[lt][ct] = __builtin_amdgcn_mfma_f32_16x16x32_bf16(
                        areg[lt][AI[s]], bf[ct], acc[lt][ct], 0, 0, 0);
        }

        // Fold: embed vid=ch*2+ct in low 5 mantissa bits, then min/duel.
        #pragma unroll
        for (int ct = 0; ct < 2; ++ct) {
            const unsigned vid = (unsigned)((ch << 1) | ct);
            #pragma unroll
            for (int lt = 0; lt < 4; ++lt)
                #pragma unroll
                for (int r = 0; r < 4; ++r) {
                    int sl = lt * 4 + r;
                    float p = __uint_as_float(
                        (__float_as_uint(acc[lt][ct][r]) & 0xFFFFFFE0u) | vid);
                    float t = fmaxf(p, b1[sl]);
                    b2[sl] = fminf(b2[sl], t);
                    b1[sl] = fminf(b1[sl], p);
                }
        }
    }

    // ---- Epilogue phase 1: exact lexicographic (score,k) reduction ----
    __syncthreads();   // wbuf dead -> red/redk alias safe
    const int cid = CH * 16 + r16;   // 32 contributors per latent
    int kslot[16];
    #pragma unroll
    for (int lt = 0; lt < 4; ++lt)
        #pragma unroll
        for (int r = 0; r < 4; ++r) {
            int sl = lt * 4 + r;
            unsigned ub = __float_as_uint(b1[sl]);
            int vid = (int)(ub & 31u);
            int k = (vid >> 1) * 64 + CH * 32 + (vid & 1) * 16 + r16;
            kslot[sl] = k;
            int lat = LH * 64 + lt * 16 + quad * 4 + r;
            red[cid * 129 + lat]  = __uint_as_float(ub & 0xFFFFFFE0u);
            redk[cid * 129 + lat] = k;
        }
    __syncthreads();
    float B1 = 0.f;
    if (tid < LPB) {
        B1 = red[tid]; int I1 = redk[tid];
        #pragma unroll 4
        for (int c = 1; c < 32; ++c) {
            float s = red[c * 129 + tid]; int k2 = redk[c * 129 + tid];
            if (s < B1 || (s == B1 && k2 < I1)) { B1 = s; I1 = k2; }
        }
        bfin[tid] = I1;
    }
    __syncthreads();
    // Phase 2: global 2nd best = min over (holder-of-winner-k ? b2 : b1)
    #pragma unroll
    for (int lt = 0; lt < 4; ++lt)
        #pragma unroll
        for (int r = 0; r < 4; ++r) {
            int sl = lt * 4 + r;
            int lat = LH * 64 + lt * 16 + quad * 4 + r;
            float b1c = __uint_as_float(__float_as_uint(b1[sl]) & 0xFFFFFFE0u);
            float b2c = __uint_as_float(__float_as_uint(b2[sl]) & 0xFFFFFFE0u);
            red[cid * 129 + lat] = (kslot[sl] == bfin[lat]) ? b2c : b1c;
        }
    __syncthreads();
    if (tid < LPB) {
        float f2 = red[tid];
        #pragma unroll 4
        for (int c = 1; c < 32; ++c) f2 = fminf(f2, red[c * 129 + tid]);
        // eps: split residual + dropped lo.lo + fp32 accum + truncation
        float eps = 1.0e-3f + 6.0e-5f * fabsf(B1);
        if (f2 - B1 < eps) {
            int pos = atomicAdd(ambn, 1);
            amb[pos] = tid;
        }
    }
    __syncthreads();

    // ---- Inline exact rescue: one wave per ambiguous latent ----
    {
        const int na = ambn[0];
        for (int e = wave; e < na; e += 4) {
            const int lat = amb[e];
            const float* xp = x + (size_t)b * (DIM * HW) + hw0 + lat;
            float xs[DIM];
            #pragma unroll
            for (int d = 0; d < DIM; ++d) xs[d] = xp[d * HW];  // wave-uniform
            float bb = FLT_MAX; int bi = 0;
            #pragma unroll 2
            for (int c = 0; c < 16; ++c) {
                int k = c * 64 + lane;
                const float4* wr = (const float4*)(w + (size_t)k * DIM);
                float a0 = 0.f, a1 = 0.f, a2 = 0.f, a3 = 0.f;
                #pragma unroll
                for (int j = 0; j < 16; ++j) {
                    float4 v = wr[j];
                    a0 += xs[4 * j]     * v.x;  a1 += xs[4 * j + 1] * v.y;
                    a2 += xs[4 * j + 2] * v.z;  a3 += xs[4 * j + 3] * v.w;
                }
                float s = wn[k] - ((a0 + a1) + (a2 + a3));
                if (s < bb) { bb = s; bi = k; }
            }
            #pragma unroll
            for (int off = 32; off > 0; off >>= 1) {   // lex (score,k) argmin
                float ob = __shfl_down(bb, off);
                int   oi = __shfl_down(bi, off);
                if (ob < bb || (ob == bb && oi < bi)) { bb = ob; bi = oi; }
            }
            if (lane == 0) bfin[lat] = bi;
        }
    }
    __syncthreads();

    // ---- Gather: out[n][:] = w[bfin][:]  (coalesced float4) ----
    float* outp = out + (size_t)blk * (LPB * DIM);
    #pragma unroll
    for (int r = 0; r < 8; ++r) {
        int idx = r * 256 + tid;             // 2048 float4 = 128x64 floats
        int row = idx >> 4, seg = idx & 15;
        int code = bfin[row];
        *(float4*)&outp[idx * 4] = *(const float4*)&w[(size_t)code * DIM + seg * 4];
    }
}

extern "C" void kernel_launch(void* const* d_in, const int* in_sizes, int n_in,
                              void* d_out, int out_size, void* d_ws, size_t ws_size,
                              hipStream_t stream) {
    const float* x = (const float*)d_in[0];
    const float* w = (const float*)d_in[1];
    float* out = (float*)d_out;
    unsigned short* WEg = (unsigned short*)d_ws;                  // 262144 B (swizzled)
    float* wn = (float*)((char*)d_ws + 262144);                   // 4096 B

    vq_prep<<<4, 256, 0, stream>>>(w, WEg, wn);
    vq_main<<<NLAT / LPB, 256, 0, stream>>>(x, w, WEg, wn, out);
}

// Round 12
// 125.801 us; speedup vs baseline: 1.0345x; 1.0345x over previous
//
#include <hip/hip_runtime.h>
#include <float.h>

// VectorQuantizer: x [64,64,32,32] f32, weight [1024,64] f32
// out[n] = weight[argmin_k ||x_n - w_k||^2]
// score = 0.5||w||^2 + (-x).w via split-bf16 MFMA, K=192 (hi.hi + lo.hi + hi.lo).
// R12: R9 tile (LPB=128, CPK=128, 8 dbuf phases) split over 512 threads:
// 8 waves x (32 lat x 64 code) tiles -> ~115 regs/wave (was ~190) ->
// launch_bounds(512,4) = 2 blocks/CU = 16 waves/CU (2x R9; R9 was VALU-issue
// + dep-latency bound at 2 waves/SIMD). Fold 4->3 ops/score via fmed3
// (b2=med3(b1,b2,p) is the exact top-2 update; distinct vids => no eq-hazard).
// B staged via global_load_lds double-buffer (prefetch one phase ahead).
// NOTE: no pointer ARRAYS into LDS (addrspacecast static-init fails on gfx950).
#define NLAT   65536
#define KCODES 1024
#define DIM    64
#define HW     1024
#define LPB    128
#define CPK    128
#define NCHUNK 8
#define XROW   136          // XE padded row (shorts): 272 B

typedef float f32x4 __attribute__((ext_vector_type(4)));
typedef short short8 __attribute__((ext_vector_type(8)));

static __device__ __forceinline__ unsigned short f2bf(float f) {
    unsigned int u = __float_as_uint(f);
    return (unsigned short)((u + 0x7fffu + ((u >> 16) & 1u)) >> 16);   // RNE
}
static __device__ __forceinline__ float bf2f(unsigned short h) {
    return __uint_as_float(((unsigned int)h) << 16);
}
static __device__ __forceinline__ void async_cp16(const void* g, void* l) {
    __builtin_amdgcn_global_load_lds(
        (const __attribute__((address_space(1))) unsigned int*)g,
        (__attribute__((address_space(3))) unsigned int*)l, 16, 0, 0);
}

// ---------------------------------------------------------------------------
// Prep: WEg[k] = 256B row of 16 swizzled 16B segs. Logical seg L: L<8 ->
// hi(d=8L..8L+7), L>=8 -> lo. Physical pos = L ^ (k & 15) (bank swizzle baked
// into global so the byte-linear DMA lands conflict-reduced for MFMA reads).
__global__ void vq_prep(const float* __restrict__ w, unsigned short* __restrict__ WEg,
                        float* __restrict__ wn) {
    int k = blockIdx.x * blockDim.x + threadIdx.x;   // 4 x 256 = 1024
    if (k >= KCODES) return;
    float s = 0.f;
    #pragma unroll
    for (int d = 0; d < DIM; ++d) { float v = w[(size_t)k * DIM + d]; s += v * v; }
    wn[k] = 0.5f * s;
    unsigned short* row = WEg + (size_t)k * 128;
    #pragma unroll
    for (int L = 0; L < 16; ++L) {
        short8 seg;
        #pragma unroll
        for (int j = 0; j < 8; ++j) {
            float v = w[(size_t)k * DIM + (L & 7) * 8 + j];
            unsigned short h = f2bf(v);
            seg[j] = (L < 8) ? (short)h : (short)f2bf(v - bf2f(h));
        }
        *(short8*)(row + ((L ^ (k & 15)) << 3)) = seg;
    }
}

// ---------------------------------------------------------------------------
// Main: 512 blocks x 512 thr (4 latent-quarters x 2 code-halves). Wave tile:
// 32 lats x 64 codes per 128-code chunk (2x4 16x16 mfma tiles, 6 K-steps).
// A-frags (negated x) pinned in regs; B dbuf'd in LDS via async DMA.
__global__ __launch_bounds__(512, 4)
void vq_main(const float* __restrict__ x, const float* __restrict__ w,
             const unsigned short* __restrict__ WEg, const float* __restrict__ wn,
             float* __restrict__ out) {
    __shared__ __align__(16) char smem[66576];
    unsigned short* XE = (unsigned short*)smem;        // [128][136] (phase 0 only)
    char* wbuf0 = smem;                                // 32KB B buf (even chunks)
    char* wbuf1 = smem + 32768;                        // 32KB B buf (odd chunks)
    float* red  = (float*)smem;                        // [32][129] f32 (post-K)
    int*   redk = (int*)(smem + 16512);                // [32][129] int (post-K)
    int*   bfin = (int*)(smem + 65536);                // [128] winner k
    int*   amb  = (int*)(smem + 66048);                // [128] ambiguous lat ids
    int*   ambn = (int*)(smem + 66560);                // count

    const int tid  = threadIdx.x;
    const int wave = tid >> 6, lane = tid & 63;
    const int r16  = lane & 15, quad = lane >> 4;
    const int LH = wave >> 1;       // latent quarter 0..3 (32 lats each)
    const int CH = wave & 1;        // code half 0..1 (64 codes each)

    const int blk = blockIdx.x;
    const int b   = blk >> 3;                 // 8 blocks per image
    const int hw0 = (blk & 7) * LPB;

    if (tid == 0) ambn[0] = 0;

    // Phase 0: convert NEGATED x tile -> XE[lat][hi 0..63 | lo 64..127]
    {
        const int lat  = tid & 127;
        const int part = tid >> 7;            // 4 channel quarters (16 ch each)
        const float* xb = x + (size_t)b * (DIM * HW) + hw0 + lat;
        #pragma unroll 8
        for (int c = 0; c < 16; ++c) {
            int chn = part * 16 + c;
            float v = -xb[chn * HW];          // negate: score = wn + (-x).w
            unsigned short h = f2bf(v);
            XE[lat * XROW + chn]      = h;
            XE[lat * XROW + 64 + chn] = f2bf(v - bf2f(h));
        }
    }
    __syncthreads();

    // A-frags: span 0=hi d0-31, 1=hi d32-63, 2=lo d0-31, 3=lo d32-63
    short8 areg[2][4];
    #pragma unroll
    for (int lt = 0; lt < 2; ++lt)
        #pragma unroll
        for (int p = 0; p < 4; ++p)
            areg[lt][p] = *(const short8*)&XE[(LH * 32 + lt * 16 + r16) * XROW + p * 32 + quad * 8];
    __syncthreads();   // XE dead -> wbuf may overwrite

    // Prefetch chunk 0 into wbuf0 (drained by the first loop-top barrier)
    {
        const char* gsrc = (const char*)WEg + wave * 4096 + lane * 16;
        char* ldst = wbuf0 + wave * 4096;
        #pragma unroll
        for (int i = 0; i < 4; ++i) async_cp16(gsrc + i * 1024, ldst + i * 1024);
    }

    float b1[8], b2[8];
    #pragma unroll
    for (int sl = 0; sl < 8; ++sl) { b1[sl] = FLT_MAX; b2[sl] = FLT_MAX; }

    for (int ch = 0; ch < NCHUNK; ++ch) {
        __syncthreads();   // drains chunk-ch DMA (issued one full phase ago)
        if (ch + 1 < NCHUNK) {   // prefetch next chunk into the other buffer
            const char* gsrc = (const char*)WEg + (ch + 1) * 32768 + wave * 4096 + lane * 16;
            char* ldst = (((ch + 1) & 1) ? wbuf1 : wbuf0) + wave * 4096;
            #pragma unroll
            for (int i = 0; i < 4; ++i) async_cp16(gsrc + i * 1024, ldst + i * 1024);
        }
        const char* cbuf = (ch & 1) ? wbuf1 : wbuf0;
        const int kb = ch * CPK;

        float wnv[4];
        #pragma unroll
        for (int ct = 0; ct < 4; ++ct)
            wnv[ct] = wn[kb + CH * 64 + ct * 16 + r16];
        f32x4 acc[2][4];
        #pragma unroll
        for (int lt = 0; lt < 2; ++lt)
            #pragma unroll
            for (int ct = 0; ct < 4; ++ct) {
                acc[lt][ct][0] = wnv[ct]; acc[lt][ct][1] = wnv[ct];
                acc[lt][ct][2] = wnv[ct]; acc[lt][ct][3] = wnv[ct];
            }

        // K=192, W-span loaded once each: (A0,W0)(A2,W0)(A1,W1)(A3,W1)(A0,W2)(A1,W3)
        const int AI[6]  = {0, 2, 1, 3, 0, 1};
        const int WSp[6] = {0, 0, 1, 1, 2, 3};
        short8 bf[4];
        #pragma unroll
        for (int s = 0; s < 6; ++s) {
            if (s == 0 || WSp[s] != WSp[s - 1]) {
                #pragma unroll
                for (int ct = 0; ct < 4; ++ct) {
                    int r = CH * 64 + ct * 16 + r16;       // local code row 0..127
                    int seg = (WSp[s] * 4 + quad) ^ r16;   // matches prep swizzle
                    bf[ct] = *(const short8*)(cbuf + r * 256 + seg * 16);
                }
            }
            #pragma unroll
            for (int lt = 0; lt < 2; ++lt)
                #pragma unroll
                for (int ct = 0; ct < 4; ++ct)
                    acc[lt][ct] = __builtin_amdgcn_mfma_f32_16x16x32_bf16(
                        areg[lt][AI[s]], bf[ct], acc[lt][ct], 0, 0, 0);
        }

        // Fold (3 ops/score): pack vid, b2 = med3(b1,b2,p), b1 = min(b1,p)
        #pragma unroll
        for (int ct = 0; ct < 4; ++ct) {
            const unsigned vid = (unsigned)((ch << 2) | ct);
            #pragma unroll
            for (int lt = 0; lt < 2; ++lt)
                #pragma unroll
                for (int r = 0; r < 4; ++r) {
                    int sl = lt * 4 + r;
                    float p = __uint_as_float(
                        (__float_as_uint(acc[lt][ct][r]) & 0xFFFFFFE0u) | vid);
                    b2[sl] = __builtin_amdgcn_fmed3f(b1[sl], b2[sl], p);
                    b1[sl] = fminf(b1[sl], p);
                }
        }
    }

    // ---- Epilogue phase 1: exact lexicographic (score,k) reduction ----
    __syncthreads();   // wbuf dead -> red/redk alias safe
    const int cid = CH * 16 + r16;   // 32 contributors per latent
    int kslot[8];
    #pragma unroll
    for (int lt = 0; lt < 2; ++lt)
        #pragma unroll
        for (int r = 0; r < 4; ++r) {
            int sl = lt * 4 + r;
            unsigned ub = __float_as_uint(b1[sl]);
            int vid = (int)(ub & 31u);
            int k = (vid >> 2) * 128 + CH * 64 + (vid & 3) * 16 + r16;
            kslot[sl] = k;
            int lat = LH * 32 + lt * 16 + quad * 4 + r;
            red[cid * 129 + lat]  = __uint_as_float(ub & 0xFFFFFFE0u);
            redk[cid * 129 + lat] = k;
        }
    __syncthreads();
    float B1 = 0.f;
    if (tid < LPB) {
        B1 = red[tid]; int I1 = redk[tid];
        #pragma unroll 4
        for (int c = 1; c < 32; ++c) {
            float s = red[c * 129 + tid]; int k2 = redk[c * 129 + tid];
            if (s < B1 || (s == B1 && k2 < I1)) { B1 = s; I1 = k2; }
        }
        bfin[tid] = I1;
    }
    __syncthreads();
    // Phase 2: global 2nd best = min over (holder-of-winner-k ? b2 : b1)
    #pragma unroll
    for (int lt = 0; lt < 2; ++lt)
        #pragma unroll
        for (int r = 0; r < 4; ++r) {
            int sl = lt * 4 + r;
            int lat = LH * 32 + lt * 16 + quad * 4 + r;
            float b1c = __uint_as_float(__float_as_uint(b1[sl]) & 0xFFFFFFE0u);
            float b2c = __uint_as_float(__float_as_uint(b2[sl]) & 0xFFFFFFE0u);
            red[cid * 129 + lat] = (kslot[sl] == bfin[lat]) ? b2c : b1c;
        }
    __syncthreads();
    if (tid < LPB) {
        float f2 = red[tid];
        #pragma unroll 4
        for (int c = 1; c < 32; ++c) f2 = fminf(f2, red[c * 129 + tid]);
        // eps: split residual + dropped lo.lo + fp32 accum + truncation
        float eps = 1.0e-3f + 6.0e-5f * fabsf(B1);
        if (f2 - B1 < eps) {
            int pos = atomicAdd(ambn, 1);
            amb[pos] = tid;
        }
    }
    __syncthreads();

    // ---- Inline exact rescue: one wave per ambiguous latent ----
    {
        const int na = ambn[0];
        for (int e = wave; e < na; e += 8) {
            const int lat = amb[e];
            const float* xp = x + (size_t)b * (DIM * HW) + hw0 + lat;
            float xs[DIM];
            #pragma unroll
            for (int d = 0; d < DIM; ++d) xs[d] = xp[d * HW];  // wave-uniform
            float bb = FLT_MAX; int bi = 0;
            #pragma unroll 2
            for (int c = 0; c < 16; ++c) {
                int k = c * 64 + lane;
                const float4* wr = (const float4*)(w + (size_t)k * DIM);
                float a0 = 0.f, a1 = 0.f, a2 = 0.f, a3 = 0.f;
                #pragma unroll
                for (int j = 0; j < 16; ++j) {
                    float4 v = wr[j];
                    a0 += xs[4 * j]     * v.x;  a1 += xs[4 * j + 1] * v.y;
                    a2 += xs[4 * j + 2] * v.z;  a3 += xs[4 * j + 3] * v.w;
                }
                float s = wn[k] - ((a0 + a1) + (a2 + a3));
                if (s < bb) { bb = s; bi = k; }
            }
            #pragma unroll
            for (int off = 32; off > 0; off >>= 1) {   // lex (score,k) argmin
                float ob = __shfl_down(bb, off);
                int   oi = __shfl_down(bi, off);
                if (ob < bb || (ob == bb && oi < bi)) { bb = ob; bi = oi; }
            }
            if (lane == 0) bfin[lat] = bi;
        }
    }
    __syncthreads();

    // ---- Gather: out[n][:] = w[bfin][:]  (coalesced float4) ----
    float* outp = out + (size_t)blk * (LPB * DIM);
    #pragma unroll
    for (int r = 0; r < 4; ++r) {
        int idx = r * 512 + tid;             // 2048 float4 = 128x64 floats
        int row = idx >> 4, seg = idx & 15;
        int code = bfin[row];
        *(float4*)&outp[idx * 4] = *(const float4*)&w[(size_t)code * DIM + seg * 4];
    }
}

extern "C" void kernel_launch(void* const* d_in, const int* in_sizes, int n_in,
                              void* d_out, int out_size, void* d_ws, size_t ws_size,
                              hipStream_t stream) {
    const float* x = (const float*)d_in[0];
    const float* w = (const float*)d_in[1];
    float* out = (float*)d_out;
    unsigned short* WEg = (unsigned short*)d_ws;                  // 262144 B (swizzled)
    float* wn = (float*)((char*)d_ws + 262144);                   // 4096 B

    vq_prep<<<4, 256, 0, stream>>>(w, WEg, wn);
    vq_main<<<NLAT / LPB, 512, 0, stream>>>(x, w, WEg, wn, out);
}

// Round 13
// 114.223 us; speedup vs baseline: 1.1394x; 1.1014x over previous
//
#include <hip/hip_runtime.h>
#include <float.h>

// VectorQuantizer: x [64,64,32,32] f32, weight [1024,64] f32
// out[n] = weight[argmin_k ||x_n - w_k||^2]
// score = 0.5||w||^2 + (-x).w via split-bf16 MFMA, K=256 FULL product
// (hi.hi + lo.hi + hi.lo + lo.lo -> only fp32-accum + 5-bit-vid truncation
// error => eps ~4e-4, few rescues). R13 = R9 structure (best measured:
// 51us; R10/11/12 occupancy variants all regressed) + parallel prep.
// B staged via global_load_lds double-buffer (prefetch one phase ahead).
// Fold embeds vid=(ch<<2)|ct (5 bits) in score's low mantissa; exact lex
// (score,k) epilogue; ambiguous latents rescored exactly inline.
// NOTE: no pointer ARRAYS into LDS (addrspacecast static-init fails on gfx950).
#define NLAT   65536
#define KCODES 1024
#define DIM    64
#define HW     1024
#define LPB    128
#define CPK    128
#define NCHUNK 8
#define XROW   136          // XE padded row (shorts): 272 B

typedef float f32x4 __attribute__((ext_vector_type(4)));
typedef short short8 __attribute__((ext_vector_type(8)));

static __device__ __forceinline__ unsigned short f2bf(float f) {
    unsigned int u = __float_as_uint(f);
    return (unsigned short)((u + 0x7fffu + ((u >> 16) & 1u)) >> 16);   // RNE
}
static __device__ __forceinline__ float bf2f(unsigned short h) {
    return __uint_as_float(((unsigned int)h) << 16);
}
static __device__ __forceinline__ void async_cp16(const void* g, void* l) {
    __builtin_amdgcn_global_load_lds(
        (const __attribute__((address_space(1))) unsigned int*)g,
        (__attribute__((address_space(3))) unsigned int*)l, 16, 0, 0);
}

// ---------------------------------------------------------------------------
// Prep: one WAVE per code (grid 256 x 256 thr = 1024 waves) -- R12's 4-block
// prep serialized on 4 CUs. Lane d loads w[k][d] (coalesced 256B), shuffle-
// reduces the norm, writes hi/lo shorts into the XOR-swizzled row layout:
// logical seg L (L<8: hi d=8L.., L>=8: lo), physical pos = L ^ (k & 15).
__global__ __launch_bounds__(256)
void vq_prep(const float* __restrict__ w, unsigned short* __restrict__ WEg,
             float* __restrict__ wn) {
    const int wave = threadIdx.x >> 6, lane = threadIdx.x & 63;
    const int k = blockIdx.x * 4 + wave;
    float v = w[(size_t)k * DIM + lane];
    float s = v * v;
    #pragma unroll
    for (int m = 32; m > 0; m >>= 1) s += __shfl_xor(s, m, 64);
    if (lane == 0) wn[k] = 0.5f * s;
    unsigned short h = f2bf(v);
    unsigned short l = f2bf(v - bf2f(h));
    unsigned short* row = WEg + (size_t)k * 128;
    const int j = lane & 7, Lh = lane >> 3, Ll = 8 + (lane >> 3);
    row[(((Lh ^ (k & 15)) << 3) | j)] = h;
    row[(((Ll ^ (k & 15)) << 3) | j)] = l;
}

// ---------------------------------------------------------------------------
// Main: 512 blocks x 256 thr (2 latent-halves x 2 code-halves). Wave tile
// 64 lats x 64 codes per 128-code chunk; A-frags (negated x) pinned in regs;
// B double-buffered in LDS via async DMA; inline exact rescue; gather.
__global__ __launch_bounds__(256, 2)
void vq_main(const float* __restrict__ x, const float* __restrict__ w,
             const unsigned short* __restrict__ WEg, const float* __restrict__ wn,
             float* __restrict__ out) {
    __shared__ __align__(16) char smem[66576];
    unsigned short* XE = (unsigned short*)smem;        // [128][136] (phase 0 only)
    char* wbuf0 = smem;                                // 32KB B buf (even chunks)
    char* wbuf1 = smem + 32768;                        // 32KB B buf (odd chunks)
    float* red  = (float*)smem;                        // [32][129] f32 (post-K)
    int*   redk = (int*)(smem + 16512);                // [32][129] int (post-K)
    int*   bfin = (int*)(smem + 65536);                // [128] winner k
    int*   amb  = (int*)(smem + 66048);                // [128] ambiguous lat ids
    int*   ambn = (int*)(smem + 66560);                // count

    const int tid  = threadIdx.x;
    const int wave = tid >> 6, lane = tid & 63;
    const int r16  = lane & 15, quad = lane >> 4;
    const int LH = wave & 1, CH = wave >> 1;

    const int blk = blockIdx.x;
    const int b   = blk >> 3;
    const int hw0 = (blk & 7) * LPB;

    if (tid == 0) ambn[0] = 0;

    // Phase 0: convert NEGATED x tile -> XE[lat][hi 0..63 | lo 64..127]
    {
        const int lat  = tid & 127;
        const int half = tid >> 7;
        const float* xb = x + (size_t)b * (DIM * HW) + hw0 + lat;
        #pragma unroll 8
        for (int c = 0; c < 32; ++c) {
            int chn = half * 32 + c;
            float v = -xb[chn * HW];          // negate: score = wn + (-x).w
            unsigned short h = f2bf(v);
            XE[lat * XROW + chn]      = h;
            XE[lat * XROW + 64 + chn] = f2bf(v - bf2f(h));
        }
    }
    __syncthreads();

    // A-frags: span 0=hi d0-31, 1=hi d32-63, 2=lo d0-31, 3=lo d32-63
    short8 areg[4][4];
    #pragma unroll
    for (int lt = 0; lt < 4; ++lt)
        #pragma unroll
        for (int p = 0; p < 4; ++p)
            areg[lt][p] = *(const short8*)&XE[(LH * 64 + lt * 16 + r16) * XROW + p * 32 + quad * 8];
    __syncthreads();   // XE dead -> wbuf may overwrite

    // Prefetch chunk 0 into wbuf0 (drained by the first loop-top barrier)
    {
        const char* gsrc = (const char*)WEg + wave * 8192 + lane * 16;
        char* ldst = wbuf0 + wave * 8192;
        #pragma unroll
        for (int i = 0; i < 8; ++i) async_cp16(gsrc + i * 1024, ldst + i * 1024);
    }

    float b1[16], b2[16];
    #pragma unroll
    for (int sl = 0; sl < 16; ++sl) { b1[sl] = FLT_MAX; b2[sl] = FLT_MAX; }

    for (int ch = 0; ch < NCHUNK; ++ch) {
        __syncthreads();   // drains chunk-ch DMA (issued one full phase ago)
        if (ch + 1 < NCHUNK) {   // prefetch next chunk into the other buffer
            const char* gsrc = (const char*)WEg + (ch + 1) * 32768 + wave * 8192 + lane * 16;
            char* ldst = (((ch + 1) & 1) ? wbuf1 : wbuf0) + wave * 8192;
            #pragma unroll
            for (int i = 0; i < 8; ++i) async_cp16(gsrc + i * 1024, ldst + i * 1024);
        }
        const char* cbuf = (ch & 1) ? wbuf1 : wbuf0;
        const int kb = ch * CPK;

        float wnv[4];
        #pragma unroll
        for (int ct = 0; ct < 4; ++ct)
            wnv[ct] = wn[kb + CH * 64 + ct * 16 + r16];
        f32x4 acc[4][4];
        #pragma unroll
        for (int lt = 0; lt < 4; ++lt)
            #pragma unroll
            for (int ct = 0; ct < 4; ++ct) {
                acc[lt][ct][0] = wnv[ct]; acc[lt][ct][1] = wnv[ct];
                acc[lt][ct][2] = wnv[ct]; acc[lt][ct][3] = wnv[ct];
            }

        // K=256 FULL product: spans 0=hi0,1=hi1,2=lo0,3=lo1; each W-span
        // loaded once, used by 2 A-spans: W0(A0,A2) W1(A1,A3) W2(A0,A2) W3(A1,A3)
        const int AI[8]  = {0, 2, 1, 3, 0, 2, 1, 3};
        const int WSp[8] = {0, 0, 1, 1, 2, 2, 3, 3};
        short8 bf[4];
        #pragma unroll
        for (int s = 0; s < 8; ++s) {
            if (s == 0 || WSp[s] != WSp[s - 1]) {
                #pragma unroll
                for (int ct = 0; ct < 4; ++ct) {
                    int r = CH * 64 + ct * 16 + r16;
                    int seg = (WSp[s] * 4 + quad) ^ r16;   // matches prep swizzle
                    bf[ct] = *(const short8*)(cbuf + r * 256 + seg * 16);
                }
            }
            #pragma unroll
            for (int lt = 0; lt < 4; ++lt)
                #pragma unroll
                for (int ct = 0; ct < 4; ++ct)
                    acc[lt][ct] = __builtin_amdgcn_mfma_f32_16x16x32_bf16(
                        areg[lt][AI[s]], bf[ct], acc[lt][ct], 0, 0, 0);
        }

        // Fold: embed vid in low 5 mantissa bits (1 op) + min/duel (3 ops)
        #pragma unroll
        for (int ct = 0; ct < 4; ++ct) {
            const unsigned vid = (unsigned)((ch << 2) | ct);
            #pragma unroll
            for (int lt = 0; lt < 4; ++lt)
                #pragma unroll
                for (int r = 0; r < 4; ++r) {
                    int sl = lt * 4 + r;
                    float p = __uint_as_float(
                        (__float_as_uint(acc[lt][ct][r]) & 0xFFFFFFE0u) | vid);
                    float t = fmaxf(p, b1[sl]);
                    b2[sl] = fminf(b2[sl], t);
                    b1[sl] = fminf(b1[sl], p);
                }
        }
    }

    // ---- Epilogue phase 1: exact lexicographic (score,k) reduction ----
    __syncthreads();   // wbuf dead -> red/redk alias safe
    const int cid = CH * 16 + r16;   // 32 contributors per latent
    int kslot[16];
    #pragma unroll
    for (int lt = 0; lt < 4; ++lt)
        #pragma unroll
        for (int r = 0; r < 4; ++r) {
            int sl = lt * 4 + r;
            unsigned ub = __float_as_uint(b1[sl]);
            int vid = (int)(ub & 31u);
            int k = (vid >> 2) * 128 + CH * 64 + (vid & 3) * 16 + r16;
            kslot[sl] = k;
            int lat = LH * 64 + lt * 16 + quad * 4 + r;
            red[cid * 129 + lat]  = __uint_as_float(ub & 0xFFFFFFE0u);
            redk[cid * 129 + lat] = k;
        }
    __syncthreads();
    float B1 = 0.f;
    if (tid < LPB) {
        B1 = red[tid]; int I1 = redk[tid];
        #pragma unroll 4
        for (int c = 1; c < 32; ++c) {
            float s = red[c * 129 + tid]; int k2 = redk[c * 129 + tid];
            if (s < B1 || (s == B1 && k2 < I1)) { B1 = s; I1 = k2; }
        }
        bfin[tid] = I1;
    }
    __syncthreads();
    // Phase 2: global 2nd best = min over (holder-of-winner-k ? b2 : b1)
    #pragma unroll
    for (int lt = 0; lt < 4; ++lt)
        #pragma unroll
        for (int r = 0; r < 4; ++r) {
            int sl = lt * 4 + r;
            int lat = LH * 64 + lt * 16 + quad * 4 + r;
            float b1c = __uint_as_float(__float_as_uint(b1[sl]) & 0xFFFFFFE0u);
            float b2c = __uint_as_float(__float_as_uint(b2[sl]) & 0xFFFFFFE0u);
            red[cid * 129 + lat] = (kslot[sl] == bfin[lat]) ? b2c : b1c;
        }
    __syncthreads();
    if (tid < LPB) {
        float f2 = red[tid];
        #pragma unroll 4
        for (int c = 1; c < 32; ++c) f2 = fminf(f2, red[c * 129 + tid]);
        // eps: split double-rounding residual + fp32 accum + 2x 5-bit vid
        // truncation (2*2^-18 rel). Full product => no dropped-term 1e-3.
        float eps = 4.0e-4f + 4.0e-5f * fabsf(B1);
        if (f2 - B1 < eps) {
            int pos = atomicAdd(ambn, 1);
            amb[pos] = tid;
        }
    }
    __syncthreads();

    // ---- Inline exact rescue: one wave per ambiguous latent ----
    {
        const int na = ambn[0];
        for (int e = wave; e < na; e += 4) {
            const int lat = amb[e];
            const float* xp = x + (size_t)b * (DIM * HW) + hw0 + lat;
            float xs[DIM];
            #pragma unroll
            for (int d = 0; d < DIM; ++d) xs[d] = xp[d * HW];  // wave-uniform
            float bb = FLT_MAX; int bi = 0;
            #pragma unroll 2
            for (int c = 0; c < 16; ++c) {
                int k = c * 64 + lane;
                const float4* wr = (const float4*)(w + (size_t)k * DIM);
                float a0 = 0.f, a1 = 0.f, a2 = 0.f, a3 = 0.f;
                #pragma unroll
                for (int j = 0; j < 16; ++j) {
                    float4 v = wr[j];
                    a0 += xs[4 * j]     * v.x;  a1 += xs[4 * j + 1] * v.y;
                    a2 += xs[4 * j + 2] * v.z;  a3 += xs[4 * j + 3] * v.w;
                }
                float s = wn[k] - ((a0 + a1) + (a2 + a3));
                if (s < bb) { bb = s; bi = k; }
            }
            #pragma unroll
            for (int off = 32; off > 0; off >>= 1) {   // lex (score,k) argmin
                float ob = __shfl_down(bb, off);
                int   oi = __shfl_down(bi, off);
                if (ob < bb || (ob == bb && oi < bi)) { bb = ob; bi = oi; }
            }
            if (lane == 0) bfin[lat] = bi;
        }
    }
    __syncthreads();

    // ---- Gather: out[n][:] = w[bfin][:]  (coalesced float4) ----
    float* outp = out + (size_t)blk * (LPB * DIM);
    #pragma unroll
    for (int r = 0; r < 8; ++r) {
        int idx = r * 256 + tid;
        int row = idx >> 4, seg = idx & 15;
        int code = bfin[row];
        *(float4*)&outp[idx * 4] = *(const float4*)&w[(size_t)code * DIM + seg * 4];
    }
}

extern "C" void kernel_launch(void* const* d_in, const int* in_sizes, int n_in,
                              void* d_out, int out_size, void* d_ws, size_t ws_size,
                              hipStream_t stream) {
    const float* x = (const float*)d_in[0];
    const float* w = (const float*)d_in[1];
    float* out = (float*)d_out;
    unsigned short* WEg = (unsigned short*)d_ws;                  // 262144 B (swizzled)
    float* wn = (float*)((char*)d_ws + 262144);                   // 4096 B

    vq_prep<<<KCODES / 4, 256, 0, stream>>>(w, WEg, wn);
    vq_main<<<NLAT / LPB, 256, 0, stream>>>(x, w, WEg, wn, out);
}

// Round 14
// 111.186 us; speedup vs baseline: 1.1705x; 1.0273x over previous
//
#include <hip/hip_runtime.h>
#include <float.h>

// VectorQuantizer: x [64,64,32,32] f32, weight [1024,64] f32
// out[n] = weight[argmin_k ||x_n - w_k||^2]
// score = 0.5||w||^2 + (-x).w via split-bf16 MFMA, K=256 FULL product
// (only fp32-accum + 5-bit-vid truncation error => eps ~4e-4, few rescues).
// R14 = R13 structure (best measured) + med3 3-op fold + 2x-parallel epilogue.
// B staged via global_load_lds double-buffer (prefetch one phase ahead).
// Fold embeds vid=(ch<<2)|ct (5 bits) in score's low mantissa; exact lex
// (score,k) epilogue; ambiguous latents rescored exactly inline.
// NOTE: no pointer ARRAYS into LDS (addrspacecast static-init fails on gfx950).
#define NLAT   65536
#define KCODES 1024
#define DIM    64
#define HW     1024
#define LPB    128
#define CPK    128
#define NCHUNK 8
#define XROW   136          // XE padded row (shorts): 272 B

typedef float f32x4 __attribute__((ext_vector_type(4)));
typedef short short8 __attribute__((ext_vector_type(8)));

static __device__ __forceinline__ unsigned short f2bf(float f) {
    unsigned int u = __float_as_uint(f);
    return (unsigned short)((u + 0x7fffu + ((u >> 16) & 1u)) >> 16);   // RNE
}
static __device__ __forceinline__ float bf2f(unsigned short h) {
    return __uint_as_float(((unsigned int)h) << 16);
}
static __device__ __forceinline__ void async_cp16(const void* g, void* l) {
    __builtin_amdgcn_global_load_lds(
        (const __attribute__((address_space(1))) unsigned int*)g,
        (__attribute__((address_space(3))) unsigned int*)l, 16, 0, 0);
}

// ---------------------------------------------------------------------------
// Prep: one WAVE per code (grid 256 x 256 thr). Lane d loads w[k][d]
// (coalesced), shuffle-reduces the norm, writes hi/lo shorts into the
// XOR-swizzled row: logical seg L (L<8: hi, L>=8: lo), phys = L ^ (k & 15).
__global__ __launch_bounds__(256)
void vq_prep(const float* __restrict__ w, unsigned short* __restrict__ WEg,
             float* __restrict__ wn) {
    const int wave = threadIdx.x >> 6, lane = threadIdx.x & 63;
    const int k = blockIdx.x * 4 + wave;
    float v = w[(size_t)k * DIM + lane];
    float s = v * v;
    #pragma unroll
    for (int m = 32; m > 0; m >>= 1) s += __shfl_xor(s, m, 64);
    if (lane == 0) wn[k] = 0.5f * s;
    unsigned short h = f2bf(v);
    unsigned short l = f2bf(v - bf2f(h));
    unsigned short* row = WEg + (size_t)k * 128;
    const int j = lane & 7, Lh = lane >> 3, Ll = 8 + (lane >> 3);
    row[(((Lh ^ (k & 15)) << 3) | j)] = h;
    row[(((Ll ^ (k & 15)) << 3) | j)] = l;
}

// ---------------------------------------------------------------------------
// Main: 512 blocks x 256 thr (2 latent-halves x 2 code-halves). Wave tile
// 64 lats x 64 codes per 128-code chunk; A-frags (negated x) pinned in regs;
// B double-buffered in LDS via async DMA; inline exact rescue; gather.
__global__ __launch_bounds__(256, 2)
void vq_main(const float* __restrict__ x, const float* __restrict__ w,
             const unsigned short* __restrict__ WEg, const float* __restrict__ wn,
             float* __restrict__ out) {
    __shared__ __align__(16) char smem[66576];
    unsigned short* XE = (unsigned short*)smem;        // [128][136] (phase 0 only)
    char* wbuf0 = smem;                                // 32KB B buf (even chunks)
    char* wbuf1 = smem + 32768;                        // 32KB B buf (odd chunks)
    float* red  = (float*)smem;                        // [32][129] f32 (post-K)
    int*   redk = (int*)(smem + 16512);                // [32][129] int (post-K)
    float* hb1  = (float*)(smem + 33024);              // [2][128] half-reduced score
    int*   hbk  = (int*)(smem + 34048);                // [2][128] half-reduced k
    int*   bfin = (int*)(smem + 65536);                // [128] winner k
    int*   amb  = (int*)(smem + 66048);                // [128] ambiguous lat ids
    int*   ambn = (int*)(smem + 66560);                // count

    const int tid  = threadIdx.x;
    const int wave = tid >> 6, lane = tid & 63;
    const int r16  = lane & 15, quad = lane >> 4;
    const int LH = wave & 1, CH = wave >> 1;

    const int blk = blockIdx.x;
    const int b   = blk >> 3;
    const int hw0 = (blk & 7) * LPB;

    if (tid == 0) ambn[0] = 0;

    // Phase 0: convert NEGATED x tile -> XE[lat][hi 0..63 | lo 64..127]
    {
        const int lat  = tid & 127;
        const int half = tid >> 7;
        const float* xb = x + (size_t)b * (DIM * HW) + hw0 + lat;
        #pragma unroll 8
        for (int c = 0; c < 32; ++c) {
            int chn = half * 32 + c;
            float v = -xb[chn * HW];          // negate: score = wn + (-x).w
            unsigned short h = f2bf(v);
            XE[lat * XROW + chn]      = h;
            XE[lat * XROW + 64 + chn] = f2bf(v - bf2f(h));
        }
    }
    __syncthreads();

    // A-frags: span 0=hi d0-31, 1=hi d32-63, 2=lo d0-31, 3=lo d32-63
    short8 areg[4][4];
    #pragma unroll
    for (int lt = 0; lt < 4; ++lt)
        #pragma unroll
        for (int p = 0; p < 4; ++p)
            areg[lt][p] = *(const short8*)&XE[(LH * 64 + lt * 16 + r16) * XROW + p * 32 + quad * 8];
    __syncthreads();   // XE dead -> wbuf may overwrite

    // Prefetch chunk 0 into wbuf0 (drained by the first loop-top barrier)
    {
        const char* gsrc = (const char*)WEg + wave * 8192 + lane * 16;
        char* ldst = wbuf0 + wave * 8192;
        #pragma unroll
        for (int i = 0; i < 8; ++i) async_cp16(gsrc + i * 1024, ldst + i * 1024);
    }

    float b1[16], b2[16];
    #pragma unroll
    for (int sl = 0; sl < 16; ++sl) { b1[sl] = FLT_MAX; b2[sl] = FLT_MAX; }

    for (int ch = 0; ch < NCHUNK; ++ch) {
        __syncthreads();   // drains chunk-ch DMA (issued one full phase ago)
        if (ch + 1 < NCHUNK) {   // prefetch next chunk into the other buffer
            const char* gsrc = (const char*)WEg + (ch + 1) * 32768 + wave * 8192 + lane * 16;
            char* ldst = (((ch + 1) & 1) ? wbuf1 : wbuf0) + wave * 8192;
            #pragma unroll
            for (int i = 0; i < 8; ++i) async_cp16(gsrc + i * 1024, ldst + i * 1024);
        }
        const char* cbuf = (ch & 1) ? wbuf1 : wbuf0;
        const int kb = ch * CPK;

        float wnv[4];
        #pragma unroll
        for (int ct = 0; ct < 4; ++ct)
            wnv[ct] = wn[kb + CH * 64 + ct * 16 + r16];
        f32x4 acc[4][4];
        #pragma unroll
        for (int lt = 0; lt < 4; ++lt)
            #pragma unroll
            for (int ct = 0; ct < 4; ++ct) {
                acc[lt][ct][0] = wnv[ct]; acc[lt][ct][1] = wnv[ct];
                acc[lt][ct][2] = wnv[ct]; acc[lt][ct][3] = wnv[ct];
            }

        // K=256 FULL product: spans 0=hi0,1=hi1,2=lo0,3=lo1; each W-span
        // loaded once, used by 2 A-spans: W0(A0,A2) W1(A1,A3) W2(A0,A2) W3(A1,A3)
        const int AI[8]  = {0, 2, 1, 3, 0, 2, 1, 3};
        const int WSp[8] = {0, 0, 1, 1, 2, 2, 3, 3};
        short8 bf[4];
        #pragma unroll
        for (int s = 0; s < 8; ++s) {
            if (s == 0 || WSp[s] != WSp[s - 1]) {
                #pragma unroll
                for (int ct = 0; ct < 4; ++ct) {
                    int r = CH * 64 + ct * 16 + r16;
                    int seg = (WSp[s] * 4 + quad) ^ r16;   // matches prep swizzle
                    bf[ct] = *(const short8*)(cbuf + r * 256 + seg * 16);
                }
            }
            #pragma unroll
            for (int lt = 0; lt < 4; ++lt)
                #pragma unroll
                for (int ct = 0; ct < 4; ++ct)
                    acc[lt][ct] = __builtin_amdgcn_mfma_f32_16x16x32_bf16(
                        areg[lt][AI[s]], bf[ct], acc[lt][ct], 0, 0, 0);
        }

        // Fold (3 ops/score): pack vid; b2 = med3(b1,b2,p) (exact top-2
        // update: p<b1 -> b1; b1<=p<=b2 -> p; p>b2 -> b2); b1 = min(b1,p).
        // Distinct vids => no exact-equal hazard.
        #pragma unroll
        for (int ct = 0; ct < 4; ++ct) {
            const unsigned vid = (unsigned)((ch << 2) | ct);
            #pragma unroll
            for (int lt = 0; lt < 4; ++lt)
                #pragma unroll
                for (int r = 0; r < 4; ++r) {
                    int sl = lt * 4 + r;
                    float p = __uint_as_float(
                        (__float_as_uint(acc[lt][ct][r]) & 0xFFFFFFE0u) | vid);
                    b2[sl] = __builtin_amdgcn_fmed3f(b1[sl], b2[sl], p);
                    b1[sl] = fminf(b1[sl], p);
                }
        }
    }

    // ---- Epilogue phase 1: exact lexicographic (score,k) reduction ----
    __syncthreads();   // wbuf dead -> red/redk alias safe
    const int cid = CH * 16 + r16;   // 32 contributors per latent
    int kslot[16];
    #pragma unroll
    for (int lt = 0; lt < 4; ++lt)
        #pragma unroll
        for (int r = 0; r < 4; ++r) {
            int sl = lt * 4 + r;
            unsigned ub = __float_as_uint(b1[sl]);
            int vid = (int)(ub & 31u);
            int k = (vid >> 2) * 128 + CH * 64 + (vid & 3) * 16 + r16;
            kslot[sl] = k;
            int lat = LH * 64 + lt * 16 + quad * 4 + r;
            red[cid * 129 + lat]  = __uint_as_float(ub & 0xFFFFFFE0u);
            redk[cid * 129 + lat] = k;
        }
    __syncthreads();
    // 2x-parallel: all 256 threads reduce 16 contributors each
    {
        const int lat = tid & 127, hf = tid >> 7;
        float s1 = red[(hf * 16) * 129 + lat]; int i1 = redk[(hf * 16) * 129 + lat];
        #pragma unroll 4
        for (int c = 1; c < 16; ++c) {
            float s = red[(hf * 16 + c) * 129 + lat];
            int  k2 = redk[(hf * 16 + c) * 129 + lat];
            if (s < s1 || (s == s1 && k2 < i1)) { s1 = s; i1 = k2; }
        }
        hb1[hf * 128 + lat] = s1; hbk[hf * 128 + lat] = i1;
    }
    __syncthreads();
    float B1 = 0.f;
    if (tid < LPB) {
        float sA = hb1[tid];       int kA = hbk[tid];
        float sB = hb1[128 + tid]; int kB = hbk[128 + tid];
        if (sB < sA || (sB == sA && kB < kA)) { sA = sB; kA = kB; }
        B1 = sA; bfin[tid] = kA;
    }
    __syncthreads();
    // Phase 2: global 2nd best = min over (holder-of-winner-k ? b2 : b1)
    #pragma unroll
    for (int lt = 0; lt < 4; ++lt)
        #pragma unroll
        for (int r = 0; r < 4; ++r) {
            int sl = lt * 4 + r;
            int lat = LH * 64 + lt * 16 + quad * 4 + r;
            float b1c = __uint_as_float(__float_as_uint(b1[sl]) & 0xFFFFFFE0u);
            float b2c = __uint_as_float(__float_as_uint(b2[sl]) & 0xFFFFFFE0u);
            red[cid * 129 + lat] = (kslot[sl] == bfin[lat]) ? b2c : b1c;
        }
    __syncthreads();
    {
        const int lat = tid & 127, hf = tid >> 7;
        float m = red[(hf * 16) * 129 + lat];
        #pragma unroll 4
        for (int c = 1; c < 16; ++c) m = fminf(m, red[(hf * 16 + c) * 129 + lat]);
        hb1[hf * 128 + lat] = m;
    }
    __syncthreads();
    if (tid < LPB) {
        float f2 = fminf(hb1[tid], hb1[128 + tid]);
        // eps: split double-rounding residual + fp32 accum + 2x 5-bit vid
        // truncation (2*2^-18 rel). Full product => no dropped-term 1e-3.
        float eps = 4.0e-4f + 4.0e-5f * fabsf(B1);
        if (f2 - B1 < eps) {
            int pos = atomicAdd(ambn, 1);
            amb[pos] = tid;
        }
    }
    __syncthreads();

    // ---- Inline exact rescue: one wave per ambiguous latent ----
    {
        const int na = ambn[0];
        for (int e = wave; e < na; e += 4) {
            const int lat = amb[e];
            const float* xp = x + (size_t)b * (DIM * HW) + hw0 + lat;
            float xs[DIM];
            #pragma unroll
            for (int d = 0; d < DIM; ++d) xs[d] = xp[d * HW];  // wave-uniform
            float bb = FLT_MAX; int bi = 0;
            #pragma unroll 2
            for (int c = 0; c < 16; ++c) {
                int k = c * 64 + lane;
                const float4* wr = (const float4*)(w + (size_t)k * DIM);
                float a0 = 0.f, a1 = 0.f, a2 = 0.f, a3 = 0.f;
                #pragma unroll
                for (int j = 0; j < 16; ++j) {
                    float4 v = wr[j];
                    a0 += xs[4 * j]     * v.x;  a1 += xs[4 * j + 1] * v.y;
                    a2 += xs[4 * j + 2] * v.z;  a3 += xs[4 * j + 3] * v.w;
                }
                float s = wn[k] - ((a0 + a1) + (a2 + a3));
                if (s < bb) { bb = s; bi = k; }
            }
            #pragma unroll
            for (int off = 32; off > 0; off >>= 1) {   // lex (score,k) argmin
                float ob = __shfl_down(bb, off);
                int   oi = __shfl_down(bi, off);
                if (ob < bb || (ob == bb && oi < bi)) { bb = ob; bi = oi; }
            }
            if (lane == 0) bfin[lat] = bi;
        }
    }
    __syncthreads();

    // ---- Gather: out[n][:] = w[bfin][:]  (coalesced float4) ----
    float* outp = out + (size_t)blk * (LPB * DIM);
    #pragma unroll
    for (int r = 0; r < 8; ++r) {
        int idx = r * 256 + tid;
        int row = idx >> 4, seg = idx & 15;
        int code = bfin[row];
        *(float4*)&outp[idx * 4] = *(const float4*)&w[(size_t)code * DIM + seg * 4];
    }
}

extern "C" void kernel_launch(void* const* d_in, const int* in_sizes, int n_in,
                              void* d_out, int out_size, void* d_ws, size_t ws_size,
                              hipStream_t stream) {
    const float* x = (const float*)d_in[0];
    const float* w = (const float*)d_in[1];
    float* out = (float*)d_out;
    unsigned short* WEg = (unsigned short*)d_ws;                  // 262144 B (swizzled)
    float* wn = (float*)((char*)d_ws + 262144);                   // 4096 B

    vq_prep<<<KCODES / 4, 256, 0, stream>>>(w, WEg, wn);
    vq_main<<<NLAT / LPB, 256, 0, stream>>>(x, w, WEg, wn, out);
}